// Round 3
// baseline (367.161 us; speedup 1.0000x reference)
//
#include <hip/hip_runtime.h>
#include <hip/hip_bf16.h>
#include <stdint.h>

// TrellisQuantizer: out[i,j,:] = tlut[(h>>5)&1023] ^ sign(h bits 15/13), h=(e+1)*e
// Memory-bound: 134 MB read + 268 MB write = 402 MB -> ~65 us floor at ~6.2 TB/s.
// This round: max MLP — all 8 per-thread loads issued before any store.

constexpr int TLUT_ENTRIES = 1024;   // 8 KiB float2 LUT, LDS-resident
constexpr int BLOCK  = 256;
constexpr int BLOCKS = 8192;
constexpr int ITERS  = 8;            // n2 = BLOCKS*BLOCK*ITERS exactly

typedef float f32x4 __attribute__((ext_vector_type(4)));

__device__ __forceinline__ f32x4 dequant_pair(uint64_t e2, const float2* slut) {
    uint32_t e0 = (uint32_t)e2;
    uint32_t e1 = (uint32_t)(e2 >> 32);
    uint32_t h0 = (e0 + 1u) * e0;
    uint32_t h1 = (e1 + 1u) * e1;
    float2 t0 = slut[(h0 >> 5) & 1023u];
    float2 t1 = slut[(h1 >> 5) & 1023u];
    f32x4 o;
    o.x = __uint_as_float(__float_as_uint(t0.x) ^ ((h0 & 0x8000u) << 16));
    o.y = __uint_as_float(__float_as_uint(t0.y) ^ ((h0 & 0x2000u) << 18));
    o.z = __uint_as_float(__float_as_uint(t1.x) ^ ((h1 & 0x8000u) << 16));
    o.w = __uint_as_float(__float_as_uint(t1.y) ^ ((h1 & 0x2000u) << 18));
    return o;
}

__global__ __launch_bounds__(BLOCK) void trellis_dequant_kernel(
    const float2*   __restrict__ tlut,
    const uint64_t* __restrict__ enc,
    f32x4*          __restrict__ out,
    int n2)
{
    __shared__ float2 slut[TLUT_ENTRIES];
    for (int j = threadIdx.x; j < TLUT_ENTRIES; j += BLOCK)
        slut[j] = tlut[j];
    __syncthreads();

    const int stride = gridDim.x * BLOCK;
    const int i0 = blockIdx.x * BLOCK + threadIdx.x;

    if (n2 == stride * ITERS) {
        // Fast path: exact trip count, all loads in flight before stores.
        uint64_t e[ITERS];
        #pragma unroll
        for (int k = 0; k < ITERS; ++k)
            e[k] = __builtin_nontemporal_load(&enc[i0 + k * stride]);
        #pragma unroll
        for (int k = 0; k < ITERS; ++k)
            __builtin_nontemporal_store(dequant_pair(e[k], slut), &out[i0 + k * stride]);
    } else {
        for (int i = i0; i < n2; i += stride) {
            uint64_t e2 = __builtin_nontemporal_load(&enc[i]);
            __builtin_nontemporal_store(dequant_pair(e2, slut), &out[i]);
        }
    }
}

extern "C" void kernel_launch(void* const* d_in, const int* in_sizes, int n_in,
                              void* d_out, int out_size, void* d_ws, size_t ws_size,
                              hipStream_t stream) {
    const float2*   tlut = (const float2*)d_in[0];     // [1024,2] fp32
    const uint64_t* enc  = (const uint64_t*)d_in[1];   // [16384,2048] int32, pair-packed
    f32x4*          out  = (f32x4*)d_out;              // [16384,2048,2] fp32 as float4

    const int n_codes = in_sizes[1];                   // 33,554,432
    const int n2 = n_codes / 2;                        // 16,777,216 pairs

    trellis_dequant_kernel<<<BLOCKS, BLOCK, 0, stream>>>(tlut, enc, out, n2);
}